// Round 7
// baseline (470.764 us; speedup 1.0000x reference)
//
#include <hip/hip_runtime.h>
#include <hip/hip_bf16.h>

// GCN 2-layer. R15: bucketed CSR build (scatter_k + p2_build_k, 2 passes over
// edges + 12.8MB bmem round-trip) replaced by minimal direct build:
//   deg_k  (1 global atomic/edge) ->
//   alloc_k (391-block scan, base via global atomic; + folded weight cast) ->
//   fill_k (csr[atomicAdd(cur[d])] = s).
// csr shrinks 12.8 -> 6.4MB exact (L2-resident in aggs); nseg interface
// unchanged so agg1/gemm2/agg2 are byte-identical to R14-proven versions.
// gemm1: manual 3-op RNE cast -> __float22bfloat162_rn (v_cvt_pk_bf16_f32).
// Round doubles as measurement: if old build held the unaccounted ~110us,
// total drops to ~220-240; if not, hidden time is fixed harness overhead.

#define FIN 256
#define HDIM 128
#define CDIM 40

typedef __attribute__((ext_vector_type(8))) short bf16x8;
typedef __attribute__((ext_vector_type(4))) float f32x4;
typedef __attribute__((ext_vector_type(2))) float f32x2;

__device__ inline short f2bf(float f) {               // RNE fp32 -> bf16
    unsigned u = __float_as_uint(f);
    unsigned r = (u + 0x7FFFu + ((u >> 16) & 1u)) >> 16;
    return (short)r;
}
__device__ inline float bflo(unsigned u) { return __uint_as_float(u << 16); }
__device__ inline float bfhi(unsigned u) { return __uint_as_float(u & 0xFFFF0000u); }
__device__ inline f32x2 unpk(unsigned u) { return (f32x2){bflo(u), bfhi(u)}; }
__device__ inline float ub0(unsigned u) { return (float)(u & 255u); }
__device__ inline float ub1(unsigned u) { return (float)((u >> 8) & 255u); }
__device__ inline float ub2(unsigned u) { return (float)((u >> 16) & 255u); }
__device__ inline float ub3(unsigned u) { return (float)(u >> 24); }

// ---- CSR build pass 1: per-node degree via global atomics ----
__global__ __launch_bounds__(1024) void deg_k(const int* __restrict__ ei, int* __restrict__ deg, int E) {
    int e = blockIdx.x * 1024 + threadIdx.x;
    if (e < E) atomicAdd(&deg[ei[E + e]], 1);
}

// ---- CSR build pass 2: block scan -> segment bases (+ folded weight cast) ----
__global__ __launch_bounds__(256) void alloc_k(const int* __restrict__ deg, int* __restrict__ total,
                                               int2* __restrict__ nseg, int* __restrict__ cur,
                                               float* __restrict__ dinv, float* __restrict__ invd,
                                               const float* __restrict__ W1, const float* __restrict__ W2,
                                               short* __restrict__ W1T, short* __restrict__ W2T, int N) {
    __shared__ int sc[256];
    __shared__ int bbase;
    const int b = blockIdx.x;
    const int tid = threadIdx.x;

    // folded castW: grid-stride over both weight matrices
    for (int idx = b * 256 + tid; idx < FIN * HDIM + 48 * HDIM; idx += gridDim.x * 256) {
        if (idx < FIN * HDIM) {
            int k = idx >> 7, n = idx & 127;
            W1T[n * FIN + k] = f2bf(W1[idx]);
        } else {
            int j = idx - FIN * HDIM;
            int c = j >> 7, k = j & 127;
            W2T[j] = (c < CDIM) ? f2bf(W2[k * CDIM + c]) : (short)0;
        }
    }

    const int i = b * 256 + tid;
    const int v = (i < N) ? deg[i] : 0;
    sc[tid] = v;
    __syncthreads();
    for (int off = 1; off < 256; off <<= 1) {
        int t = (tid >= off) ? sc[tid - off] : 0;
        __syncthreads();
        sc[tid] += t;
        __syncthreads();
    }
    const int incl = sc[tid];
    const int excl = incl - v;
    if (tid == 255) bbase = atomicAdd(total, incl);
    __syncthreads();
    const int base = bbase;
    if (i < N) {
        nseg[i] = make_int2(base + excl, v);
        cur[i] = base + excl;
        float dg = (float)(v + 1);
        dinv[i] = rsqrtf(dg);
        invd[i] = 1.0f / dg;
    }
}

// ---- CSR build pass 3: scatter edges to exact segments ----
__global__ __launch_bounds__(1024) void fill_k(const int* __restrict__ ei, int* __restrict__ cur,
                                               int* __restrict__ csr, int E) {
    int e = blockIdx.x * 1024 + threadIdx.x;
    if (e < E) {
        int s = ei[e];
        int d = ei[E + e];
        int pos = atomicAdd(&cur[d], 1);
        csr[pos] = s;
    }
}

// GEMM1 (MFMA bf16): T1 = X(Nx256) @ W1(256x128), quantized to int8 per-row.
// Outputs: T1q (u8 rows, 128B), scl[i]=rowmax/127, wsc[i]=scl[i]*dinv[i].
#define LDSTRIDE 40
__global__ __launch_bounds__(256) void gemm1_mfma_k(const float* __restrict__ X,
                                                    const short* __restrict__ W1T,
                                                    const float* __restrict__ dinv,
                                                    unsigned char* __restrict__ T1q,
                                                    float* __restrict__ scl,
                                                    float* __restrict__ wsc, int N) {
    __shared__ short SH[128 * LDSTRIDE * 2];
    short* As = SH;
    short* Bs = SH + 128 * LDSTRIDE;
    const int tid = threadIdx.x;
    const int lane = tid & 63;
    const int wid = tid >> 6;
    const int w0 = wid & 1, w1 = wid >> 1;
    const int quad = lane >> 4;
    const int l16 = lane & 15;
    const int rowbase = blockIdx.x * 128;
    const int sr = tid >> 1;
    const int sh = tid & 1;

    f32x4 acc[4][4];
#pragma unroll
    for (int a = 0; a < 4; a++)
#pragma unroll
        for (int b = 0; b < 4; b++) acc[a][b] = (f32x4){0.f, 0.f, 0.f, 0.f};

    const int arow = min(rowbase + sr, N - 1);
    const float* xsrc = X + (size_t)arow * FIN + sh * 16;
    const int4* bsrc = (const int4*)(W1T + (size_t)sr * FIN + sh * 16);

    for (int k0 = 0; k0 < FIN; k0 += 32) {
        float vals[16];
        *(float4*)&vals[0]  = *(const float4*)(xsrc + k0);
        *(float4*)&vals[4]  = *(const float4*)(xsrc + k0 + 4);
        *(float4*)&vals[8]  = *(const float4*)(xsrc + k0 + 8);
        *(float4*)&vals[12] = *(const float4*)(xsrc + k0 + 12);
        __hip_bfloat162 tmp2[8];
#pragma unroll
        for (int c = 0; c < 8; c++)
            tmp2[c] = __float22bfloat162_rn(make_float2(vals[2 * c], vals[2 * c + 1]));
        ((int4*)&As[sr * LDSTRIDE + sh * 16])[0] = ((int4*)tmp2)[0];
        ((int4*)&As[sr * LDSTRIDE + sh * 16])[1] = ((int4*)tmp2)[1];
        int4 b0 = bsrc[k0 >> 3];
        int4 b1 = bsrc[(k0 >> 3) + 1];
        ((int4*)&Bs[sr * LDSTRIDE + sh * 16])[0] = b0;
        ((int4*)&Bs[sr * LDSTRIDE + sh * 16])[1] = b1;
        __syncthreads();

        bf16x8 afr[4], bfr[4];
#pragma unroll
        for (int mt = 0; mt < 4; mt++)
            afr[mt] = *(const bf16x8*)&As[(w1 * 64 + mt * 16 + l16) * LDSTRIDE + quad * 8];
#pragma unroll
        for (int nt = 0; nt < 4; nt++)
            bfr[nt] = *(const bf16x8*)&Bs[(w0 * 64 + nt * 16 + l16) * LDSTRIDE + quad * 8];
#pragma unroll
        for (int mt = 0; mt < 4; mt++)
#pragma unroll
            for (int nt = 0; nt < 4; nt++)
                acc[mt][nt] = __builtin_amdgcn_mfma_f32_16x16x32_bf16(afr[mt], bfr[nt], acc[mt][nt], 0, 0, 0);
        __syncthreads();
    }

    // ---- int8 per-row quantization epilogue ----
    unsigned char* qbuf = (unsigned char*)SH;                 // 16KB staging
    float* rmaxb = (float*)((char*)SH + 16384);               // [2][128] half-row maxes
#pragma unroll
    for (int mt = 0; mt < 4; mt++) {
#pragma unroll
        for (int r = 0; r < 4; r++) {
            float m = fabsf(acc[mt][0][r]);
            m = fmaxf(m, fabsf(acc[mt][1][r]));
            m = fmaxf(m, fabsf(acc[mt][2][r]));
            m = fmaxf(m, fabsf(acc[mt][3][r]));
#pragma unroll
            for (int off = 1; off < 16; off <<= 1) m = fmaxf(m, __shfl_xor(m, off));
            rmaxb[w0 * 128 + w1 * 64 + mt * 16 + quad * 4 + r] = m;
        }
    }
    __syncthreads();
    if (tid < 128) {
        int grow = rowbase + tid;
        if (grow < N) {
            float rv = fmaxf(rmaxb[tid], rmaxb[128 + tid]);
            float s = rv * (1.f / 127.f);
            scl[grow] = s;
            wsc[grow] = s * dinv[grow];
        }
    }
#pragma unroll
    for (int mt = 0; mt < 4; mt++) {
#pragma unroll
        for (int r = 0; r < 4; r++) {
            const int row = w1 * 64 + mt * 16 + quad * 4 + r;
            float rv = fmaxf(rmaxb[row], rmaxb[128 + row]);
            float qinv = rv > 0.f ? 127.f / rv : 0.f;
#pragma unroll
            for (int nt = 0; nt < 4; nt++) {
                int qi = (int)rintf(acc[mt][nt][r] * qinv) + 128;
                qi = qi < 0 ? 0 : (qi > 255 ? 255 : qi);
                qbuf[row * 128 + w0 * 64 + nt * 16 + l16] = (unsigned char)qi;
            }
        }
    }
    __syncthreads();
#pragma unroll
    for (int it = 0; it < 4; it++) {
        int idx = tid + it * 256;            // 1024 x 16B = 16KB
        int row = idx >> 3;
        if (rowbase + row < N)
            ((uint4*)(T1q + (size_t)(rowbase + row) * 128))[idx & 7] = ((const uint4*)qbuf)[idx];
    }
}

// agg1: wave/node, int8 gather (uint2 = 8 cols/lane), writes Hb bf16 packed.
// acc_c = sum_j wsc[s_j]*u_jc ; true sum recovered via -128*asum bias.
__global__ __launch_bounds__(256) void agg1_k(const unsigned char* __restrict__ T1q, const int2* __restrict__ nseg,
                                              const int* __restrict__ csr, const float* __restrict__ wsc,
                                              const float* __restrict__ scl, const float* __restrict__ dinv,
                                              const float* __restrict__ invd, const float* __restrict__ b1,
                                              unsigned* __restrict__ Hb, int N) {
    const int lane = threadIdx.x & 63;
    const int quad = lane >> 4;
    const int ql = lane & 15;
    const int i = blockIdx.x * 4 + (threadIdx.x >> 6);
    if (i >= N) return;
    const int2 sg = nseg[i];
    const int e0 = sg.x, deg = sg.y;
    int sv = 0; float wv = 0.f;
    if (lane < deg) { sv = csr[e0 + lane]; wv = wsc[sv]; }   // lanes>=deg: wv=0

    const uint2* rowp = (const uint2*)T1q;   // 16 uint2 per 128B row
    uint2 us = rowp[i * 16 + ql];            // self row
    const float sscale = scl[i];

    f32x2 acc[4]; float asum = 0.f;
#pragma unroll
    for (int t = 0; t < 4; t++) acc[t] = (f32x2){0.f, 0.f};

    const int dmain = deg < 64 ? deg : 64;
    for (int j = 0; j < dmain; j += 16) {
        const int i0 = j + quad, i1 = j + 4 + quad, i2 = j + 8 + quad, i3 = j + 12 + quad;
        int s0 = __shfl(sv, i0); int s1 = __shfl(sv, i1);
        int s2 = __shfl(sv, i2); int s3 = __shfl(sv, i3);
        float w0 = __shfl(wv, i0); float w1 = __shfl(wv, i1);
        float w2 = __shfl(wv, i2); float w3 = __shfl(wv, i3);
        w0 = (i0 < dmain) ? w0 : 0.f;
        w1 = (i1 < dmain) ? w1 : 0.f;
        w2 = (i2 < dmain) ? w2 : 0.f;
        w3 = (i3 < dmain) ? w3 : 0.f;
        uint2 u0 = rowp[s0 * 16 + ql];
        uint2 u1 = rowp[s1 * 16 + ql];
        uint2 u2 = rowp[s2 * 16 + ql];
        uint2 u3 = rowp[s3 * 16 + ql];
        asum += w0 + w1 + w2 + w3;
        f32x2 W0 = (f32x2){w0, w0}, W1v = (f32x2){w1, w1}, W2v = (f32x2){w2, w2}, W3v = (f32x2){w3, w3};
        acc[0] += W0 * (f32x2){ub0(u0.x), ub1(u0.x)} + W1v * (f32x2){ub0(u1.x), ub1(u1.x)}
                + W2v * (f32x2){ub0(u2.x), ub1(u2.x)} + W3v * (f32x2){ub0(u3.x), ub1(u3.x)};
        acc[1] += W0 * (f32x2){ub2(u0.x), ub3(u0.x)} + W1v * (f32x2){ub2(u1.x), ub3(u1.x)}
                + W2v * (f32x2){ub2(u2.x), ub3(u2.x)} + W3v * (f32x2){ub2(u3.x), ub3(u3.x)};
        acc[2] += W0 * (f32x2){ub0(u0.y), ub1(u0.y)} + W1v * (f32x2){ub0(u1.y), ub1(u1.y)}
                + W2v * (f32x2){ub0(u2.y), ub1(u2.y)} + W3v * (f32x2){ub0(u3.y), ub1(u3.y)};
        acc[3] += W0 * (f32x2){ub2(u0.y), ub3(u0.y)} + W1v * (f32x2){ub2(u1.y), ub3(u1.y)}
                + W2v * (f32x2){ub2(u2.y), ub3(u2.y)} + W3v * (f32x2){ub2(u3.y), ub3(u3.y)};
    }
    const int eEnd = e0 + deg;
    for (int e = e0 + 64; e < eEnd; e += 4) {          // rare tail deg > 64
        int idx = e + quad;
        int cl = idx < eEnd ? idx : eEnd - 1;
        int sj = csr[cl];
        float wj = (idx < eEnd) ? wsc[sj] : 0.f;
        uint2 u = rowp[sj * 16 + ql];
        asum += wj;
        f32x2 Wj = (f32x2){wj, wj};
        acc[0] += Wj * (f32x2){ub0(u.x), ub1(u.x)};
        acc[1] += Wj * (f32x2){ub2(u.x), ub3(u.x)};
        acc[2] += Wj * (f32x2){ub0(u.y), ub1(u.y)};
        acc[3] += Wj * (f32x2){ub2(u.y), ub3(u.y)};
    }
#pragma unroll
    for (int t = 0; t < 4; t++) {
        acc[t].x += __shfl_xor(acc[t].x, 16); acc[t].y += __shfl_xor(acc[t].y, 16);
        acc[t].x += __shfl_xor(acc[t].x, 32); acc[t].y += __shfl_xor(acc[t].y, 32);
    }
    asum += __shfl_xor(asum, 16);
    asum += __shfl_xor(asum, 32);

    const float di = dinv[i];
    const float sf2 = invd[i] * sscale;
    const float K = -128.f * (sf2 + di * asum);
    float4 bA = *(const float4*)(b1 + ql * 8);
    float4 bB = *(const float4*)(b1 + ql * 8 + 4);
    float o0 = fmaxf(bA.x + sf2 * ub0(us.x) + di * acc[0].x + K, 0.f);
    float o1 = fmaxf(bA.y + sf2 * ub1(us.x) + di * acc[0].y + K, 0.f);
    float o2 = fmaxf(bA.z + sf2 * ub2(us.x) + di * acc[1].x + K, 0.f);
    float o3 = fmaxf(bA.w + sf2 * ub3(us.x) + di * acc[1].y + K, 0.f);
    float o4 = fmaxf(bB.x + sf2 * ub0(us.y) + di * acc[2].x + K, 0.f);
    float o5 = fmaxf(bB.y + sf2 * ub1(us.y) + di * acc[2].y + K, 0.f);
    float o6 = fmaxf(bB.z + sf2 * ub2(us.y) + di * acc[3].x + K, 0.f);
    float o7 = fmaxf(bB.w + sf2 * ub3(us.y) + di * acc[3].y + K, 0.f);
    uint4 pk;
    pk.x = ((unsigned)(unsigned short)f2bf(o0)) | (((unsigned)(unsigned short)f2bf(o1)) << 16);
    pk.y = ((unsigned)(unsigned short)f2bf(o2)) | (((unsigned)(unsigned short)f2bf(o3)) << 16);
    pk.z = ((unsigned)(unsigned short)f2bf(o4)) | (((unsigned)(unsigned short)f2bf(o5)) << 16);
    pk.w = ((unsigned)(unsigned short)f2bf(o6)) | (((unsigned)(unsigned short)f2bf(o7)) << 16);
    if (quad == 0) ((uint4*)(Hb + (size_t)i * 64))[ql] = pk;
}

// GEMM2 (MFMA bf16): T2 = H(Nx128 bf16) @ W2T(48x128)^T, int8-quantized
// per-row into 64B-aligned rows (cols 40..63 pad = 128, self-cancelling).
__global__ __launch_bounds__(256) void gemm2_mfma_k(const short* __restrict__ Hb,
                                                    const short* __restrict__ W2T,
                                                    const float* __restrict__ dinv,
                                                    unsigned char* __restrict__ T2q,
                                                    float* __restrict__ scl2,
                                                    float* __restrict__ wsc2, int N) {
    __shared__ short As[128 * LDSTRIDE];
    __shared__ short Bs[48 * LDSTRIDE];
    const int tid = threadIdx.x;
    const int lane = tid & 63;
    const int wid = tid >> 6;
    const int quad = lane >> 4;
    const int l16 = lane & 15;
    const int rowbase = blockIdx.x * 128;
    const int sr = tid >> 1;
    const int sh = tid & 1;

    f32x4 acc[2][3];
#pragma unroll
    for (int a = 0; a < 2; a++)
#pragma unroll
        for (int b = 0; b < 3; b++) acc[a][b] = (f32x4){0.f, 0.f, 0.f, 0.f};

    const int arow = min(rowbase + sr, N - 1);
    const int4* asrc = (const int4*)(Hb + (size_t)arow * HDIM + sh * 16);
    const int br = tid >> 1, bh = tid & 1;   // for tid < 96
    const int4* bsrc = (const int4*)(W2T + br * HDIM + bh * 16);

    for (int k0 = 0; k0 < HDIM; k0 += 32) {
        int4 a0 = asrc[k0 >> 3];
        int4 a1 = asrc[(k0 >> 3) + 1];
        ((int4*)&As[sr * LDSTRIDE + sh * 16])[0] = a0;
        ((int4*)&As[sr * LDSTRIDE + sh * 16])[1] = a1;
        if (tid < 96) {
            int4 b0 = bsrc[k0 >> 3];
            int4 b1 = bsrc[(k0 >> 3) + 1];
            ((int4*)&Bs[br * LDSTRIDE + bh * 16])[0] = b0;
            ((int4*)&Bs[br * LDSTRIDE + bh * 16])[1] = b1;
        }
        __syncthreads();
        bf16x8 afr[2], bfr[3];
#pragma unroll
        for (int mt = 0; mt < 2; mt++)
            afr[mt] = *(const bf16x8*)&As[(wid * 32 + mt * 16 + l16) * LDSTRIDE + quad * 8];
#pragma unroll
        for (int nt = 0; nt < 3; nt++)
            bfr[nt] = *(const bf16x8*)&Bs[(nt * 16 + l16) * LDSTRIDE + quad * 8];
#pragma unroll
        for (int mt = 0; mt < 2; mt++)
#pragma unroll
            for (int nt = 0; nt < 3; nt++)
                acc[mt][nt] = __builtin_amdgcn_mfma_f32_16x16x32_bf16(afr[mt], bfr[nt], acc[mt][nt], 0, 0, 0);
        __syncthreads();
    }

    // ---- int8 per-row quantization epilogue ----
    unsigned char* qbuf = (unsigned char*)As;                 // 8KB staging
#pragma unroll
    for (int mt = 0; mt < 2; mt++) {
#pragma unroll
        for (int r = 0; r < 4; r++) {
            float m = fmaxf(fmaxf(fabsf(acc[mt][0][r]), fabsf(acc[mt][1][r])), fabsf(acc[mt][2][r]));
#pragma unroll
            for (int off = 1; off < 16; off <<= 1) m = fmaxf(m, __shfl_xor(m, off));
            const int row = wid * 32 + mt * 16 + quad * 4 + r;
            const int grow = rowbase + row;
            const float qinv = m > 0.f ? 127.f / m : 0.f;
            if (l16 == 0 && grow < N) {
                float s = m * (1.f / 127.f);
                scl2[grow] = s;
                wsc2[grow] = s * dinv[grow];
            }
            int q0 = (int)rintf(acc[mt][0][r] * qinv) + 128;
            int q1 = (int)rintf(acc[mt][1][r] * qinv) + 128;
            int q2 = (int)rintf(acc[mt][2][r] * qinv) + 128;
            q0 = q0 < 0 ? 0 : (q0 > 255 ? 255 : q0);
            q1 = q1 < 0 ? 0 : (q1 > 255 ? 255 : q1);
            q2 = q2 < 0 ? 0 : (q2 > 255 ? 255 : q2);
            qbuf[row * 64 + l16]      = (unsigned char)q0;
            qbuf[row * 64 + 16 + l16] = (unsigned char)q1;
            qbuf[row * 64 + 32 + l16] = (unsigned char)q2;
        }
    }
    for (int idx = tid; idx < 2048; idx += 256)               // pad cols 48..63
        qbuf[(idx >> 4) * 64 + 48 + (idx & 15)] = (unsigned char)128;
    __syncthreads();
#pragma unroll
    for (int it = 0; it < 2; it++) {
        int idx = tid + it * 256;            // 512 x 16B = 8KB
        int row = idx >> 2;
        if (rowbase + row < N)
            ((uint4*)(T2q + (size_t)(rowbase + row) * 64))[idx & 3] = ((const uint4*)qbuf)[idx];
    }
}

// agg2: wave/node, int8 64B rows (1 cache line), mirror of agg1 loop:
// oct groups x uint2, grain 16, wsc2/scl2 tables, -128 bias correction.
__global__ __launch_bounds__(256) void agg2_k(const unsigned char* __restrict__ T2q, const int2* __restrict__ nseg,
                                              const int* __restrict__ csr, const float* __restrict__ wsc2,
                                              const float* __restrict__ scl2, const float* __restrict__ dinv,
                                              const float* __restrict__ invd, const float* __restrict__ b2,
                                              float* __restrict__ OUT, int N) {
    const int lane = threadIdx.x & 63;
    const int oct = lane >> 3;
    const int olr = lane & 7;
    const int i = blockIdx.x * 4 + (threadIdx.x >> 6);
    if (i >= N) return;
    const int2 sg = nseg[i];
    const int e0 = sg.x, deg = sg.y;
    int sv = 0; float wv = 0.f;
    if (lane < deg) { sv = csr[e0 + lane]; wv = wsc2[sv]; }

    const uint2* rowp = (const uint2*)T2q;   // 8 uint2 per 64B row
    uint2 us = rowp[i * 8 + olr];            // self row (cols olr*8..+7)
    const float sscale = scl2[i];

    f32x2 acc[4]; float asum = 0.f;
#pragma unroll
    for (int t = 0; t < 4; t++) acc[t] = (f32x2){0.f, 0.f};

    const int dmain = deg < 64 ? deg : 64;
    for (int j = 0; j < dmain; j += 16) {
        const int i0 = j + oct, i1 = j + 8 + oct;
        int s0 = __shfl(sv, i0); int s1 = __shfl(sv, i1);
        float w0 = __shfl(wv, i0); float w1 = __shfl(wv, i1);
        w0 = (i0 < dmain) ? w0 : 0.f;
        w1 = (i1 < dmain) ? w1 : 0.f;
        uint2 u0 = rowp[s0 * 8 + olr];
        uint2 u1 = rowp[s1 * 8 + olr];
        asum += w0 + w1;
        f32x2 W0 = (f32x2){w0, w0}, W1v = (f32x2){w1, w1};
        acc[0] += W0 * (f32x2){ub0(u0.x), ub1(u0.x)} + W1v * (f32x2){ub0(u1.x), ub1(u1.x)};
        acc[1] += W0 * (f32x2){ub2(u0.x), ub3(u0.x)} + W1v * (f32x2){ub2(u1.x), ub3(u1.x)};
        acc[2] += W0 * (f32x2){ub0(u0.y), ub1(u0.y)} + W1v * (f32x2){ub0(u1.y), ub1(u1.y)};
        acc[3] += W0 * (f32x2){ub2(u0.y), ub3(u0.y)} + W1v * (f32x2){ub2(u1.y), ub3(u1.y)};
    }
    const int eEnd = e0 + deg;
    for (int e = e0 + 64; e < eEnd; e += 8) {          // rare tail deg > 64
        int idx = e + oct;
        int cl = idx < eEnd ? idx : eEnd - 1;
        int sj = csr[cl];
        float wj = (idx < eEnd) ? wsc2[sj] : 0.f;
        uint2 u = rowp[sj * 8 + olr];
        asum += wj;
        f32x2 Wj = (f32x2){wj, wj};
        acc[0] += Wj * (f32x2){ub0(u.x), ub1(u.x)};
        acc[1] += Wj * (f32x2){ub2(u.x), ub3(u.x)};
        acc[2] += Wj * (f32x2){ub0(u.y), ub1(u.y)};
        acc[3] += Wj * (f32x2){ub2(u.y), ub3(u.y)};
    }
#pragma unroll
    for (int t = 0; t < 4; t++) {
        acc[t].x += __shfl_xor(acc[t].x, 8);  acc[t].y += __shfl_xor(acc[t].y, 8);
        acc[t].x += __shfl_xor(acc[t].x, 16); acc[t].y += __shfl_xor(acc[t].y, 16);
        acc[t].x += __shfl_xor(acc[t].x, 32); acc[t].y += __shfl_xor(acc[t].y, 32);
    }
    asum += __shfl_xor(asum, 8);
    asum += __shfl_xor(asum, 16);
    asum += __shfl_xor(asum, 32);

    if (oct == 0 && olr < 5) {               // cols olr*8..+7 (40 total)
        const float di = dinv[i];
        const float sf2 = invd[i] * sscale;
        const float K = -128.f * (sf2 + di * asum);
        float4 bA = *(const float4*)(b2 + olr * 8);
        float4 bB = *(const float4*)(b2 + olr * 8 + 4);
        float4 oA, oB;
        oA.x = bA.x + sf2 * ub0(us.x) + di * acc[0].x + K;
        oA.y = bA.y + sf2 * ub1(us.x) + di * acc[0].y + K;
        oA.z = bA.z + sf2 * ub2(us.x) + di * acc[1].x + K;
        oA.w = bA.w + sf2 * ub3(us.x) + di * acc[1].y + K;
        oB.x = bB.x + sf2 * ub0(us.y) + di * acc[2].x + K;
        oB.y = bB.y + sf2 * ub1(us.y) + di * acc[2].y + K;
        oB.z = bB.z + sf2 * ub2(us.y) + di * acc[3].x + K;
        oB.w = bB.w + sf2 * ub3(us.y) + di * acc[3].y + K;
        *(float4*)(OUT + (size_t)i * CDIM + olr * 8) = oA;
        *(float4*)(OUT + (size_t)i * CDIM + olr * 8 + 4) = oB;
    }
}

extern "C" void kernel_launch(void* const* d_in, const int* in_sizes, int n_in,
                              void* d_out, int out_size, void* d_ws, size_t ws_size,
                              hipStream_t stream) {
    const float* x   = (const float*)d_in[0];
    const int*   ei  = (const int*)d_in[1];     // int32 in harness
    const float* W1  = (const float*)d_in[2];
    const float* b1  = (const float*)d_in[3];
    const float* W2  = (const float*)d_in[4];
    const float* b2  = (const float*)d_in[5];
    float*       out = (float*)d_out;

    const int Hd  = in_sizes[3];            // 128
    const int Fin = in_sizes[2] / Hd;       // 256
    const int N   = in_sizes[0] / Fin;      // 100000
    const int E   = in_sizes[1] / 2;        // 1600000

    const int NBUCK = (N + 255) / 256;      // 391 blocks for alloc_k
    const int NBE   = (E + 1023) / 1024;    // 1563 blocks for deg/fill

    char* base = (char*)d_ws;
    size_t off = 0;
    auto alloc = [&](size_t bytes) -> void* {
        void* p = base + off;
        off += (bytes + 255) & ~(size_t)255;
        return p;
    };
    unsigned char* t1q  = (unsigned char*)alloc((size_t)N * 128);
    int*      deg  = (int*)alloc(((size_t)N + 64) * 4);   // +total counter at [N]
    int*      cur  = (int*)alloc((size_t)N * 4);
    int*      csr  = (int*)alloc((size_t)E * 4);
    int2*     nseg = (int2*)alloc((size_t)N * 8);
    float*    dinv = (float*)alloc((size_t)N * 4);
    float*    invd = (float*)alloc((size_t)N * 4);
    float*    scl  = (float*)alloc((size_t)N * 4);
    float*    wsc  = (float*)alloc((size_t)N * 4);
    float*    scl2 = (float*)alloc((size_t)N * 4);
    float*    wsc2 = (float*)alloc((size_t)N * 4);
    short*    W1T  = (short*)alloc((size_t)HDIM * FIN * 2);
    short*    W2T  = (short*)alloc((size_t)48 * HDIM * 2);
    unsigned* hb   = (unsigned*)alloc((size_t)N * HDIM * 2);
    unsigned char* t2q = (unsigned char*)alloc((size_t)N * 64);
    int* total = deg + N;

    hipMemsetAsync(deg, 0, ((size_t)N + 64) * 4, stream);
    deg_k<<<NBE, 1024, 0, stream>>>(ei, deg, E);
    alloc_k<<<NBUCK, 256, 0, stream>>>(deg, total, nseg, cur, dinv, invd, W1, W2, W1T, W2T, N);
    fill_k<<<NBE, 1024, 0, stream>>>(ei, cur, csr, E);

    gemm1_mfma_k<<<(N + 127) / 128, 256, 0, stream>>>(x, W1T, dinv, t1q, scl, wsc, N);
    agg1_k<<<(N + 3) / 4, 256, 0, stream>>>(t1q, nseg, csr, wsc, scl, dinv, invd, b1, hb, N);
    gemm2_mfma_k<<<(N + 127) / 128, 256, 0, stream>>>((const short*)hb, W2T, dinv, t2q, scl2, wsc2, N);
    agg2_k<<<(N + 3) / 4, 256, 0, stream>>>(t2q, nseg, csr, wsc2, scl2, dinv, invd, b2, out, N);
}

// Round 8
// 379.019 us; speedup vs baseline: 1.2421x; 1.2421x over previous
//
#include <hip/hip_runtime.h>
#include <hip/hip_bf16.h>

// GCN 2-layer. R16: revert to R14's bucketed CSR build (R15 proved it was
// ~10-15us; naive fill_k was 134us of 4B-scattered-write line amplification).
// New insight: aggs are TA-REQUEST-rate bound (~0.8 req/cy/CU), not byte
// bound — int8 cut bytes 2.4x but time only 1.2x at equal request count.
// So: widen lane loads to uint4 and narrow groups: agg1 = 8 lanes/row
// (8 requests per 128B row, was 16); agg2 = 4 lanes/row (4 requests per
// 64B row, was 8). Same math/bias-correction; reduce across octs/groups.
// gemm1 keeps R15's cvt_pk bf16 cast. gemm2/T2q int8 unchanged from R14.

#define FIN 256
#define HDIM 128
#define CDIM 40
#define CAP 8192          // per-bucket edge capacity (mean 4096)
#define EC 8192           // edges per block in scatter

typedef __attribute__((ext_vector_type(8))) short bf16x8;
typedef __attribute__((ext_vector_type(4))) float f32x4;
typedef __attribute__((ext_vector_type(2))) float f32x2;

__device__ inline short f2bf(float f) {               // RNE fp32 -> bf16
    unsigned u = __float_as_uint(f);
    unsigned r = (u + 0x7FFFu + ((u >> 16) & 1u)) >> 16;
    return (short)r;
}
__device__ inline float bflo(unsigned u) { return __uint_as_float(u << 16); }
__device__ inline float bfhi(unsigned u) { return __uint_as_float(u & 0xFFFF0000u); }
__device__ inline f32x2 unpk(unsigned u) { return (f32x2){bflo(u), bfhi(u)}; }
__device__ inline float ub0(unsigned u) { return (float)(u & 255u); }
__device__ inline float ub1(unsigned u) { return (float)((u >> 8) & 255u); }
__device__ inline float ub2(unsigned u) { return (float)((u >> 16) & 255u); }
__device__ inline float ub3(unsigned u) { return (float)(u >> 24); }

// ---- scatter: per-block LDS hist -> global bucket-base alloc -> scatter ----
__global__ __launch_bounds__(1024) void scatter_k(const int* __restrict__ ei, int* __restrict__ gcnt,
                                                  int* __restrict__ bmem, int E, int NBUCK) {
    __shared__ int hist[512];
    __shared__ int base[512];
    const int tid = threadIdx.x;
    for (int t = tid; t < NBUCK; t += 1024) hist[t] = 0;
    __syncthreads();
    const int e0 = blockIdx.x * EC;
    const int e1 = min(E, e0 + EC);
    for (int e = e0 + tid; e < e1; e += 1024) atomicAdd(&hist[ei[E + e] >> 8], 1);
    __syncthreads();
    for (int t = tid; t < NBUCK; t += 1024) base[t] = atomicAdd(&gcnt[t], hist[t]);
    __syncthreads();
    for (int e = e0 + tid; e < e1; e += 1024) {
        int s = ei[e];
        int d = ei[E + e];
        int b = d >> 8;
        int pos = atomicAdd(&base[b], 1);
        bmem[b * CAP + pos] = s | ((d & 255) << 20);   // s < 2^20 (N=100000)
    }
}

// ---- per-bucket CSR build (+ folded weight cast), coalesced writes ----
__global__ __launch_bounds__(256) void p2_build_k(const int* __restrict__ bmem, const int* __restrict__ bcnt,
                                                  int* __restrict__ csr, int2* __restrict__ nseg,
                                                  float* __restrict__ dinv, float* __restrict__ invd,
                                                  const float* __restrict__ W1, const float* __restrict__ W2,
                                                  short* __restrict__ W1T, short* __restrict__ W2T, int N) {
    __shared__ int hist[256], cur[256], sc[256];
    __shared__ int stage[CAP];
    const int b = blockIdx.x;
    const int tid = threadIdx.x;

    // folded castW: grid-stride over both weight matrices
    for (int idx = b * 256 + tid; idx < FIN * HDIM + 48 * HDIM; idx += gridDim.x * 256) {
        if (idx < FIN * HDIM) {
            int k = idx >> 7, n = idx & 127;
            W1T[n * FIN + k] = f2bf(W1[idx]);
        } else {
            int j = idx - FIN * HDIM;
            int c = j >> 7, k = j & 127;
            W2T[j] = (c < CDIM) ? f2bf(W2[k * CDIM + c]) : (short)0;
        }
    }

    int cnt = bcnt[b];
    if (cnt > CAP) cnt = CAP;
    const int* src = bmem + b * CAP;
    hist[tid] = 0;
    __syncthreads();
    for (int j = tid; j < cnt; j += 256) atomicAdd(&hist[src[j] >> 20], 1);
    __syncthreads();
    int v = hist[tid];
    sc[tid] = v;
    __syncthreads();
    for (int off = 1; off < 256; off <<= 1) {
        int t = (tid >= off) ? sc[tid - off] : 0;
        __syncthreads();
        sc[tid] += t;
        __syncthreads();
    }
    int excl = sc[tid] - v;
    cur[tid] = excl;
    int i = b * 256 + tid;
    if (i < N) {
        nseg[i] = make_int2(b * CAP + excl, v);
        float dg = (float)(v + 1);
        dinv[i] = rsqrtf(dg);
        invd[i] = 1.0f / dg;
    }
    __syncthreads();
    for (int j = tid; j < cnt; j += 256) {
        int rec = src[j];
        int pos = atomicAdd(&cur[rec >> 20], 1);
        stage[pos] = rec & 0xFFFFF;
    }
    __syncthreads();
    int* dst = csr + b * CAP;
    for (int j = tid; j < cnt; j += 256) dst[j] = stage[j];
}

// GEMM1 (MFMA bf16): T1 = X(Nx256) @ W1(256x128), quantized to int8 per-row.
// Outputs: T1q (u8 rows, 128B), scl[i]=rowmax/127, wsc[i]=scl[i]*dinv[i].
#define LDSTRIDE 40
__global__ __launch_bounds__(256) void gemm1_mfma_k(const float* __restrict__ X,
                                                    const short* __restrict__ W1T,
                                                    const float* __restrict__ dinv,
                                                    unsigned char* __restrict__ T1q,
                                                    float* __restrict__ scl,
                                                    float* __restrict__ wsc, int N) {
    __shared__ short SH[128 * LDSTRIDE * 2];
    short* As = SH;
    short* Bs = SH + 128 * LDSTRIDE;
    const int tid = threadIdx.x;
    const int lane = tid & 63;
    const int wid = tid >> 6;
    const int w0 = wid & 1, w1 = wid >> 1;
    const int quad = lane >> 4;
    const int l16 = lane & 15;
    const int rowbase = blockIdx.x * 128;
    const int sr = tid >> 1;
    const int sh = tid & 1;

    f32x4 acc[4][4];
#pragma unroll
    for (int a = 0; a < 4; a++)
#pragma unroll
        for (int b = 0; b < 4; b++) acc[a][b] = (f32x4){0.f, 0.f, 0.f, 0.f};

    const int arow = min(rowbase + sr, N - 1);
    const float* xsrc = X + (size_t)arow * FIN + sh * 16;
    const int4* bsrc = (const int4*)(W1T + (size_t)sr * FIN + sh * 16);

    for (int k0 = 0; k0 < FIN; k0 += 32) {
        float vals[16];
        *(float4*)&vals[0]  = *(const float4*)(xsrc + k0);
        *(float4*)&vals[4]  = *(const float4*)(xsrc + k0 + 4);
        *(float4*)&vals[8]  = *(const float4*)(xsrc + k0 + 8);
        *(float4*)&vals[12] = *(const float4*)(xsrc + k0 + 12);
        __hip_bfloat162 tmp2[8];
#pragma unroll
        for (int c = 0; c < 8; c++)
            tmp2[c] = __float22bfloat162_rn(make_float2(vals[2 * c], vals[2 * c + 1]));
        ((int4*)&As[sr * LDSTRIDE + sh * 16])[0] = ((int4*)tmp2)[0];
        ((int4*)&As[sr * LDSTRIDE + sh * 16])[1] = ((int4*)tmp2)[1];
        int4 b0 = bsrc[k0 >> 3];
        int4 b1 = bsrc[(k0 >> 3) + 1];
        ((int4*)&Bs[sr * LDSTRIDE + sh * 16])[0] = b0;
        ((int4*)&Bs[sr * LDSTRIDE + sh * 16])[1] = b1;
        __syncthreads();

        bf16x8 afr[4], bfr[4];
#pragma unroll
        for (int mt = 0; mt < 4; mt++)
            afr[mt] = *(const bf16x8*)&As[(w1 * 64 + mt * 16 + l16) * LDSTRIDE + quad * 8];
#pragma unroll
        for (int nt = 0; nt < 4; nt++)
            bfr[nt] = *(const bf16x8*)&Bs[(w0 * 64 + nt * 16 + l16) * LDSTRIDE + quad * 8];
#pragma unroll
        for (int mt = 0; mt < 4; mt++)
#pragma unroll
            for (int nt = 0; nt < 4; nt++)
                acc[mt][nt] = __builtin_amdgcn_mfma_f32_16x16x32_bf16(afr[mt], bfr[nt], acc[mt][nt], 0, 0, 0);
        __syncthreads();
    }

    // ---- int8 per-row quantization epilogue ----
    unsigned char* qbuf = (unsigned char*)SH;                 // 16KB staging
    float* rmaxb = (float*)((char*)SH + 16384);               // [2][128] half-row maxes
#pragma unroll
    for (int mt = 0; mt < 4; mt++) {
#pragma unroll
        for (int r = 0; r < 4; r++) {
            float m = fabsf(acc[mt][0][r]);
            m = fmaxf(m, fabsf(acc[mt][1][r]));
            m = fmaxf(m, fabsf(acc[mt][2][r]));
            m = fmaxf(m, fabsf(acc[mt][3][r]));
#pragma unroll
            for (int off = 1; off < 16; off <<= 1) m = fmaxf(m, __shfl_xor(m, off));
            rmaxb[w0 * 128 + w1 * 64 + mt * 16 + quad * 4 + r] = m;
        }
    }
    __syncthreads();
    if (tid < 128) {
        int grow = rowbase + tid;
        if (grow < N) {
            float rv = fmaxf(rmaxb[tid], rmaxb[128 + tid]);
            float s = rv * (1.f / 127.f);
            scl[grow] = s;
            wsc[grow] = s * dinv[grow];
        }
    }
#pragma unroll
    for (int mt = 0; mt < 4; mt++) {
#pragma unroll
        for (int r = 0; r < 4; r++) {
            const int row = w1 * 64 + mt * 16 + quad * 4 + r;
            float rv = fmaxf(rmaxb[row], rmaxb[128 + row]);
            float qinv = rv > 0.f ? 127.f / rv : 0.f;
#pragma unroll
            for (int nt = 0; nt < 4; nt++) {
                int qi = (int)rintf(acc[mt][nt][r] * qinv) + 128;
                qi = qi < 0 ? 0 : (qi > 255 ? 255 : qi);
                qbuf[row * 128 + w0 * 64 + nt * 16 + l16] = (unsigned char)qi;
            }
        }
    }
    __syncthreads();
#pragma unroll
    for (int it = 0; it < 4; it++) {
        int idx = tid + it * 256;            // 1024 x 16B = 16KB
        int row = idx >> 3;
        if (rowbase + row < N)
            ((uint4*)(T1q + (size_t)(rowbase + row) * 128))[idx & 7] = ((const uint4*)qbuf)[idx];
    }
}

// agg1: wave/node, int8 gather. 8 lanes/row (oct) x uint4 = 8 requests per
// 128B row (halved vs 16x uint2). Grain-16: 2 neighbors/lane/iter. Writes
// Hb bf16 packed. -128*asum bias correction as before.
__global__ __launch_bounds__(256) void agg1_k(const unsigned char* __restrict__ T1q, const int2* __restrict__ nseg,
                                              const int* __restrict__ csr, const float* __restrict__ wsc,
                                              const float* __restrict__ scl, const float* __restrict__ dinv,
                                              const float* __restrict__ invd, const float* __restrict__ b1,
                                              unsigned* __restrict__ Hb, int N) {
    const int lane = threadIdx.x & 63;
    const int oct = lane >> 3;               // 8 octs = 8 neighbors in flight
    const int olr = lane & 7;                // cols olr*16 .. olr*16+15
    const int i = blockIdx.x * 4 + (threadIdx.x >> 6);
    if (i >= N) return;
    const int2 sg = nseg[i];
    const int e0 = sg.x, deg = sg.y;
    int sv = 0; float wv = 0.f;
    if (lane < deg) { sv = csr[e0 + lane]; wv = wsc[sv]; }   // lanes>=deg: wv=0

    const uint4* rowp = (const uint4*)T1q;   // 8 uint4 per 128B row
    uint4 us = rowp[i * 8 + olr];            // self row chunk
    const float sscale = scl[i];

    f32x2 acc[8]; float asum = 0.f;
#pragma unroll
    for (int t = 0; t < 8; t++) acc[t] = (f32x2){0.f, 0.f};

    const int dmain = deg < 64 ? deg : 64;
    for (int j = 0; j < dmain; j += 16) {
        const int i0 = j + oct, i1 = j + 8 + oct;
        int s0 = __shfl(sv, i0); int s1 = __shfl(sv, i1);
        float w0 = __shfl(wv, i0); float w1 = __shfl(wv, i1);
        w0 = (i0 < dmain) ? w0 : 0.f;
        w1 = (i1 < dmain) ? w1 : 0.f;
        uint4 u0 = rowp[s0 * 8 + olr];
        uint4 u1 = rowp[s1 * 8 + olr];
        asum += w0 + w1;
        f32x2 W0 = (f32x2){w0, w0}, W1v = (f32x2){w1, w1};
        acc[0] += W0 * (f32x2){ub0(u0.x), ub1(u0.x)} + W1v * (f32x2){ub0(u1.x), ub1(u1.x)};
        acc[1] += W0 * (f32x2){ub2(u0.x), ub3(u0.x)} + W1v * (f32x2){ub2(u1.x), ub3(u1.x)};
        acc[2] += W0 * (f32x2){ub0(u0.y), ub1(u0.y)} + W1v * (f32x2){ub0(u1.y), ub1(u1.y)};
        acc[3] += W0 * (f32x2){ub2(u0.y), ub3(u0.y)} + W1v * (f32x2){ub2(u1.y), ub3(u1.y)};
        acc[4] += W0 * (f32x2){ub0(u0.z), ub1(u0.z)} + W1v * (f32x2){ub0(u1.z), ub1(u1.z)};
        acc[5] += W0 * (f32x2){ub2(u0.z), ub3(u0.z)} + W1v * (f32x2){ub2(u1.z), ub3(u1.z)};
        acc[6] += W0 * (f32x2){ub0(u0.w), ub1(u0.w)} + W1v * (f32x2){ub0(u1.w), ub1(u1.w)};
        acc[7] += W0 * (f32x2){ub2(u0.w), ub3(u0.w)} + W1v * (f32x2){ub2(u1.w), ub3(u1.w)};
    }
    const int eEnd = e0 + deg;
    for (int e = e0 + 64; e < eEnd; e += 16) {         // rare tail deg > 64
        int idx0 = e + oct, idx1 = e + 8 + oct;
        int cl0 = idx0 < eEnd ? idx0 : eEnd - 1;
        int cl1 = idx1 < eEnd ? idx1 : eEnd - 1;
        int sj0 = csr[cl0];
        int sj1 = csr[cl1];
        float w0 = (idx0 < eEnd) ? wsc[sj0] : 0.f;
        float w1 = (idx1 < eEnd) ? wsc[sj1] : 0.f;
        uint4 u0 = rowp[sj0 * 8 + olr];
        uint4 u1 = rowp[sj1 * 8 + olr];
        asum += w0 + w1;
        f32x2 W0 = (f32x2){w0, w0}, W1v = (f32x2){w1, w1};
        acc[0] += W0 * (f32x2){ub0(u0.x), ub1(u0.x)} + W1v * (f32x2){ub0(u1.x), ub1(u1.x)};
        acc[1] += W0 * (f32x2){ub2(u0.x), ub3(u0.x)} + W1v * (f32x2){ub2(u1.x), ub3(u1.x)};
        acc[2] += W0 * (f32x2){ub0(u0.y), ub1(u0.y)} + W1v * (f32x2){ub0(u1.y), ub1(u1.y)};
        acc[3] += W0 * (f32x2){ub2(u0.y), ub3(u0.y)} + W1v * (f32x2){ub2(u1.y), ub3(u1.y)};
        acc[4] += W0 * (f32x2){ub0(u0.z), ub1(u0.z)} + W1v * (f32x2){ub0(u1.z), ub1(u1.z)};
        acc[5] += W0 * (f32x2){ub2(u0.z), ub3(u0.z)} + W1v * (f32x2){ub2(u1.z), ub3(u1.z)};
        acc[6] += W0 * (f32x2){ub0(u0.w), ub1(u0.w)} + W1v * (f32x2){ub0(u1.w), ub1(u1.w)};
        acc[7] += W0 * (f32x2){ub2(u0.w), ub3(u0.w)} + W1v * (f32x2){ub2(u1.w), ub3(u1.w)};
    }
#pragma unroll
    for (int t = 0; t < 8; t++) {
        acc[t].x += __shfl_xor(acc[t].x, 8);  acc[t].y += __shfl_xor(acc[t].y, 8);
        acc[t].x += __shfl_xor(acc[t].x, 16); acc[t].y += __shfl_xor(acc[t].y, 16);
        acc[t].x += __shfl_xor(acc[t].x, 32); acc[t].y += __shfl_xor(acc[t].y, 32);
    }
    asum += __shfl_xor(asum, 8);
    asum += __shfl_xor(asum, 16);
    asum += __shfl_xor(asum, 32);

    const float di = dinv[i];
    const float sf2 = invd[i] * sscale;
    const float K = -128.f * (sf2 + di * asum);
    float4 bA = *(const float4*)(b1 + olr * 16);
    float4 bB = *(const float4*)(b1 + olr * 16 + 4);
    float4 bC = *(const float4*)(b1 + olr * 16 + 8);
    float4 bD = *(const float4*)(b1 + olr * 16 + 12);
    float o0  = fmaxf(bA.x + sf2 * ub0(us.x) + di * acc[0].x + K, 0.f);
    float o1  = fmaxf(bA.y + sf2 * ub1(us.x) + di * acc[0].y + K, 0.f);
    float o2  = fmaxf(bA.z + sf2 * ub2(us.x) + di * acc[1].x + K, 0.f);
    float o3  = fmaxf(bA.w + sf2 * ub3(us.x) + di * acc[1].y + K, 0.f);
    float o4  = fmaxf(bB.x + sf2 * ub0(us.y) + di * acc[2].x + K, 0.f);
    float o5  = fmaxf(bB.y + sf2 * ub1(us.y) + di * acc[2].y + K, 0.f);
    float o6  = fmaxf(bB.z + sf2 * ub2(us.y) + di * acc[3].x + K, 0.f);
    float o7  = fmaxf(bB.w + sf2 * ub3(us.y) + di * acc[3].y + K, 0.f);
    float o8  = fmaxf(bC.x + sf2 * ub0(us.z) + di * acc[4].x + K, 0.f);
    float o9  = fmaxf(bC.y + sf2 * ub1(us.z) + di * acc[4].y + K, 0.f);
    float o10 = fmaxf(bC.z + sf2 * ub2(us.z) + di * acc[5].x + K, 0.f);
    float o11 = fmaxf(bC.w + sf2 * ub3(us.z) + di * acc[5].y + K, 0.f);
    float o12 = fmaxf(bD.x + sf2 * ub0(us.w) + di * acc[6].x + K, 0.f);
    float o13 = fmaxf(bD.y + sf2 * ub1(us.w) + di * acc[6].y + K, 0.f);
    float o14 = fmaxf(bD.z + sf2 * ub2(us.w) + di * acc[7].x + K, 0.f);
    float o15 = fmaxf(bD.w + sf2 * ub3(us.w) + di * acc[7].y + K, 0.f);
    uint4 pk0, pk1;
    pk0.x = ((unsigned)(unsigned short)f2bf(o0))  | (((unsigned)(unsigned short)f2bf(o1))  << 16);
    pk0.y = ((unsigned)(unsigned short)f2bf(o2))  | (((unsigned)(unsigned short)f2bf(o3))  << 16);
    pk0.z = ((unsigned)(unsigned short)f2bf(o4))  | (((unsigned)(unsigned short)f2bf(o5))  << 16);
    pk0.w = ((unsigned)(unsigned short)f2bf(o6))  | (((unsigned)(unsigned short)f2bf(o7))  << 16);
    pk1.x = ((unsigned)(unsigned short)f2bf(o8))  | (((unsigned)(unsigned short)f2bf(o9))  << 16);
    pk1.y = ((unsigned)(unsigned short)f2bf(o10)) | (((unsigned)(unsigned short)f2bf(o11)) << 16);
    pk1.z = ((unsigned)(unsigned short)f2bf(o12)) | (((unsigned)(unsigned short)f2bf(o13)) << 16);
    pk1.w = ((unsigned)(unsigned short)f2bf(o14)) | (((unsigned)(unsigned short)f2bf(o15)) << 16);
    if (oct == 0) {
        ((uint4*)(Hb + (size_t)i * 64))[olr * 2]     = pk0;
        ((uint4*)(Hb + (size_t)i * 64))[olr * 2 + 1] = pk1;
    }
}

// GEMM2 (MFMA bf16): T2 = H(Nx128 bf16) @ W2T(48x128)^T, int8-quantized
// per-row into 64B-aligned rows (cols 40..63 pad = 128, self-cancelling).
__global__ __launch_bounds__(256) void gemm2_mfma_k(const short* __restrict__ Hb,
                                                    const short* __restrict__ W2T,
                                                    const float* __restrict__ dinv,
                                                    unsigned char* __restrict__ T2q,
                                                    float* __restrict__ scl2,
                                                    float* __restrict__ wsc2, int N) {
    __shared__ short As[128 * LDSTRIDE];
    __shared__ short Bs[48 * LDSTRIDE];
    const int tid = threadIdx.x;
    const int lane = tid & 63;
    const int wid = tid >> 6;
    const int quad = lane >> 4;
    const int l16 = lane & 15;
    const int rowbase = blockIdx.x * 128;
    const int sr = tid >> 1;
    const int sh = tid & 1;

    f32x4 acc[2][3];
#pragma unroll
    for (int a = 0; a < 2; a++)
#pragma unroll
        for (int b = 0; b < 3; b++) acc[a][b] = (f32x4){0.f, 0.f, 0.f, 0.f};

    const int arow = min(rowbase + sr, N - 1);
    const int4* asrc = (const int4*)(Hb + (size_t)arow * HDIM + sh * 16);
    const int br = tid >> 1, bh = tid & 1;   // for tid < 96
    const int4* bsrc = (const int4*)(W2T + br * HDIM + bh * 16);

    for (int k0 = 0; k0 < HDIM; k0 += 32) {
        int4 a0 = asrc[k0 >> 3];
        int4 a1 = asrc[(k0 >> 3) + 1];
        ((int4*)&As[sr * LDSTRIDE + sh * 16])[0] = a0;
        ((int4*)&As[sr * LDSTRIDE + sh * 16])[1] = a1;
        if (tid < 96) {
            int4 b0 = bsrc[k0 >> 3];
            int4 b1 = bsrc[(k0 >> 3) + 1];
            ((int4*)&Bs[br * LDSTRIDE + bh * 16])[0] = b0;
            ((int4*)&Bs[br * LDSTRIDE + bh * 16])[1] = b1;
        }
        __syncthreads();
        bf16x8 afr[2], bfr[3];
#pragma unroll
        for (int mt = 0; mt < 2; mt++)
            afr[mt] = *(const bf16x8*)&As[(wid * 32 + mt * 16 + l16) * LDSTRIDE + quad * 8];
#pragma unroll
        for (int nt = 0; nt < 3; nt++)
            bfr[nt] = *(const bf16x8*)&Bs[(nt * 16 + l16) * LDSTRIDE + quad * 8];
#pragma unroll
        for (int mt = 0; mt < 2; mt++)
#pragma unroll
            for (int nt = 0; nt < 3; nt++)
                acc[mt][nt] = __builtin_amdgcn_mfma_f32_16x16x32_bf16(afr[mt], bfr[nt], acc[mt][nt], 0, 0, 0);
        __syncthreads();
    }

    // ---- int8 per-row quantization epilogue ----
    unsigned char* qbuf = (unsigned char*)As;                 // 8KB staging
#pragma unroll
    for (int mt = 0; mt < 2; mt++) {
#pragma unroll
        for (int r = 0; r < 4; r++) {
            float m = fmaxf(fmaxf(fabsf(acc[mt][0][r]), fabsf(acc[mt][1][r])), fabsf(acc[mt][2][r]));
#pragma unroll
            for (int off = 1; off < 16; off <<= 1) m = fmaxf(m, __shfl_xor(m, off));
            const int row = wid * 32 + mt * 16 + quad * 4 + r;
            const int grow = rowbase + row;
            const float qinv = m > 0.f ? 127.f / m : 0.f;
            if (l16 == 0 && grow < N) {
                float s = m * (1.f / 127.f);
                scl2[grow] = s;
                wsc2[grow] = s * dinv[grow];
            }
            int q0 = (int)rintf(acc[mt][0][r] * qinv) + 128;
            int q1 = (int)rintf(acc[mt][1][r] * qinv) + 128;
            int q2 = (int)rintf(acc[mt][2][r] * qinv) + 128;
            q0 = q0 < 0 ? 0 : (q0 > 255 ? 255 : q0);
            q1 = q1 < 0 ? 0 : (q1 > 255 ? 255 : q1);
            q2 = q2 < 0 ? 0 : (q2 > 255 ? 255 : q2);
            qbuf[row * 64 + l16]      = (unsigned char)q0;
            qbuf[row * 64 + 16 + l16] = (unsigned char)q1;
            qbuf[row * 64 + 32 + l16] = (unsigned char)q2;
        }
    }
    for (int idx = tid; idx < 2048; idx += 256)               // pad cols 48..63
        qbuf[(idx >> 4) * 64 + 48 + (idx & 15)] = (unsigned char)128;
    __syncthreads();
#pragma unroll
    for (int it = 0; it < 2; it++) {
        int idx = tid + it * 256;            // 512 x 16B = 8KB
        int row = idx >> 2;
        if (rowbase + row < N)
            ((uint4*)(T2q + (size_t)(rowbase + row) * 64))[idx & 3] = ((const uint4*)qbuf)[idx];
    }
}

// agg2: wave/node, int8 64B rows. 4 lanes/row (grp of 16) x uint4 = 4
// requests per row (halved vs 8x uint2). 16 neighbors in flight per iter.
__global__ __launch_bounds__(256) void agg2_k(const unsigned char* __restrict__ T2q, const int2* __restrict__ nseg,
                                              const int* __restrict__ csr, const float* __restrict__ wsc2,
                                              const float* __restrict__ scl2, const float* __restrict__ dinv,
                                              const float* __restrict__ invd, const float* __restrict__ b2,
                                              float* __restrict__ OUT, int N) {
    const int lane = threadIdx.x & 63;
    const int grp = lane >> 2;               // 16 groups = 16 neighbors in flight
    const int gl = lane & 3;                 // cols gl*16 .. gl*16+15
    const int i = blockIdx.x * 4 + (threadIdx.x >> 6);
    if (i >= N) return;
    const int2 sg = nseg[i];
    const int e0 = sg.x, deg = sg.y;
    int sv = 0; float wv = 0.f;
    if (lane < deg) { sv = csr[e0 + lane]; wv = wsc2[sv]; }

    const uint4* rowp = (const uint4*)T2q;   // 4 uint4 per 64B row
    uint4 us = rowp[i * 4 + gl];             // self row chunk
    const float sscale = scl2[i];

    f32x2 acc[8]; float asum = 0.f;
#pragma unroll
    for (int t = 0; t < 8; t++) acc[t] = (f32x2){0.f, 0.f};

    const int dmain = deg < 64 ? deg : 64;
    for (int j = 0; j < dmain; j += 16) {
        const int i0 = j + grp;
        int s0 = __shfl(sv, i0);
        float w0 = __shfl(wv, i0);
        w0 = (i0 < dmain) ? w0 : 0.f;
        uint4 u0 = rowp[s0 * 4 + gl];
        asum += w0;
        f32x2 W0 = (f32x2){w0, w0};
        acc[0] += W0 * (f32x2){ub0(u0.x), ub1(u0.x)};
        acc[1] += W0 * (f32x2){ub2(u0.x), ub3(u0.x)};
        acc[2] += W0 * (f32x2){ub0(u0.y), ub1(u0.y)};
        acc[3] += W0 * (f32x2){ub2(u0.y), ub3(u0.y)};
        acc[4] += W0 * (f32x2){ub0(u0.z), ub1(u0.z)};
        acc[5] += W0 * (f32x2){ub2(u0.z), ub3(u0.z)};
        acc[6] += W0 * (f32x2){ub0(u0.w), ub1(u0.w)};
        acc[7] += W0 * (f32x2){ub2(u0.w), ub3(u0.w)};
    }
    const int eEnd = e0 + deg;
    for (int e = e0 + 64; e < eEnd; e += 16) {         // rare tail deg > 64
        int idx = e + grp;
        int cl = idx < eEnd ? idx : eEnd - 1;
        int sj = csr[cl];
        float wj = (idx < eEnd) ? wsc2[sj] : 0.f;
        uint4 u0 = rowp[sj * 4 + gl];
        asum += wj;
        f32x2 W0 = (f32x2){wj, wj};
        acc[0] += W0 * (f32x2){ub0(u0.x), ub1(u0.x)};
        acc[1] += W0 * (f32x2){ub2(u0.x), ub3(u0.x)};
        acc[2] += W0 * (f32x2){ub0(u0.y), ub1(u0.y)};
        acc[3] += W0 * (f32x2){ub2(u0.y), ub3(u0.y)};
        acc[4] += W0 * (f32x2){ub0(u0.z), ub1(u0.z)};
        acc[5] += W0 * (f32x2){ub2(u0.z), ub3(u0.z)};
        acc[6] += W0 * (f32x2){ub0(u0.w), ub1(u0.w)};
        acc[7] += W0 * (f32x2){ub2(u0.w), ub3(u0.w)};
    }
#pragma unroll
    for (int t = 0; t < 8; t++) {
        acc[t].x += __shfl_xor(acc[t].x, 4);  acc[t].y += __shfl_xor(acc[t].y, 4);
        acc[t].x += __shfl_xor(acc[t].x, 8);  acc[t].y += __shfl_xor(acc[t].y, 8);
        acc[t].x += __shfl_xor(acc[t].x, 16); acc[t].y += __shfl_xor(acc[t].y, 16);
        acc[t].x += __shfl_xor(acc[t].x, 32); acc[t].y += __shfl_xor(acc[t].y, 32);
    }
    asum += __shfl_xor(asum, 4);
    asum += __shfl_xor(asum, 8);
    asum += __shfl_xor(asum, 16);
    asum += __shfl_xor(asum, 32);

    if (grp == 0 && gl < 3) {                // cols gl*16..+15; valid < 40
        const float di = dinv[i];
        const float sf2 = invd[i] * sscale;
        const float K = -128.f * (sf2 + di * asum);
        float* dst = OUT + (size_t)i * CDIM + gl * 16;
        float4 bA = *(const float4*)(b2 + gl * 16);
        float4 bB = *(const float4*)(b2 + gl * 16 + 4);
        float4 oA, oB;
        oA.x = bA.x + sf2 * ub0(us.x) + di * acc[0].x + K;
        oA.y = bA.y + sf2 * ub1(us.x) + di * acc[0].y + K;
        oA.z = bA.z + sf2 * ub2(us.x) + di * acc[1].x + K;
        oA.w = bA.w + sf2 * ub3(us.x) + di * acc[1].y + K;
        oB.x = bB.x + sf2 * ub0(us.y) + di * acc[2].x + K;
        oB.y = bB.y + sf2 * ub1(us.y) + di * acc[2].y + K;
        oB.z = bB.z + sf2 * ub2(us.y) + di * acc[3].x + K;
        oB.w = bB.w + sf2 * ub3(us.y) + di * acc[3].y + K;
        *(float4*)dst = oA;
        *(float4*)(dst + 4) = oB;
        if (gl < 2) {                        // cols gl*16+8..+15 also valid
            float4 bC = *(const float4*)(b2 + gl * 16 + 8);
            float4 bD = *(const float4*)(b2 + gl * 16 + 12);
            float4 oC, oD;
            oC.x = bC.x + sf2 * ub0(us.z) + di * acc[4].x + K;
            oC.y = bC.y + sf2 * ub1(us.z) + di * acc[4].y + K;
            oC.z = bC.z + sf2 * ub2(us.z) + di * acc[5].x + K;
            oC.w = bC.w + sf2 * ub3(us.z) + di * acc[5].y + K;
            oD.x = bD.x + sf2 * ub0(us.w) + di * acc[6].x + K;
            oD.y = bD.y + sf2 * ub1(us.w) + di * acc[6].y + K;
            oD.z = bD.z + sf2 * ub2(us.w) + di * acc[7].x + K;
            oD.w = bD.w + sf2 * ub3(us.w) + di * acc[7].y + K;
            *(float4*)(dst + 8) = oC;
            *(float4*)(dst + 12) = oD;
        }
    }
}

extern "C" void kernel_launch(void* const* d_in, const int* in_sizes, int n_in,
                              void* d_out, int out_size, void* d_ws, size_t ws_size,
                              hipStream_t stream) {
    const float* x   = (const float*)d_in[0];
    const int*   ei  = (const int*)d_in[1];     // int32 in harness
    const float* W1  = (const float*)d_in[2];
    const float* b1  = (const float*)d_in[3];
    const float* W2  = (const float*)d_in[4];
    const float* b2  = (const float*)d_in[5];
    float*       out = (float*)d_out;

    const int Hd  = in_sizes[3];            // 128
    const int Fin = in_sizes[2] / Hd;       // 256
    const int N   = in_sizes[0] / Fin;      // 100000
    const int E   = in_sizes[1] / 2;        // 1600000

    const int NBUCK = (N + 255) / 256;      // 391
    const int NB1   = (E + EC - 1) / EC;    // 196

    char* base = (char*)d_ws;
    size_t off = 0;
    auto alloc = [&](size_t bytes) -> void* {
        void* p = base + off;
        off += (bytes + 255) & ~(size_t)255;
        return p;
    };
    // region A: bmem (prep only), overlaid later by t1q (gemm1 onward)
    size_t bmemB = (size_t)NBUCK * CAP * 4;
    size_t t1qB  = (size_t)N * 128;
    size_t regA  = bmemB > t1qB ? bmemB : t1qB;
    char* pA = (char*)alloc(regA);
    int*           bmem = (int*)pA;
    unsigned char* t1q  = (unsigned char*)pA;

    int*      gcnt = (int*)alloc((size_t)NBUCK * 4);
    int*      csr  = (int*)alloc((size_t)NBUCK * CAP * 4);
    int2*     nseg = (int2*)alloc((size_t)N * 8);
    float*    dinv = (float*)alloc((size_t)N * 4);
    float*    invd = (float*)alloc((size_t)N * 4);
    float*    scl  = (float*)alloc((size_t)N * 4);
    float*    wsc  = (float*)alloc((size_t)N * 4);
    float*    scl2 = (float*)alloc((size_t)N * 4);
    float*    wsc2 = (float*)alloc((size_t)N * 4);
    short*    W1T  = (short*)alloc((size_t)HDIM * FIN * 2);
    short*    W2T  = (short*)alloc((size_t)48 * HDIM * 2);
    unsigned* hb   = (unsigned*)alloc((size_t)N * HDIM * 2);
    unsigned char* t2q = (unsigned char*)alloc((size_t)N * 64);

    hipMemsetAsync(gcnt, 0, (size_t)NBUCK * 4, stream);
    scatter_k<<<NB1, 1024, 0, stream>>>(ei, gcnt, bmem, E, NBUCK);
    p2_build_k<<<NBUCK, 256, 0, stream>>>(bmem, gcnt, csr, nseg, dinv, invd, W1, W2, W1T, W2T, N);

    gemm1_mfma_k<<<(N + 127) / 128, 256, 0, stream>>>(x, W1T, dinv, t1q, scl, wsc, N);
    agg1_k<<<(N + 3) / 4, 256, 0, stream>>>(t1q, nseg, csr, wsc, scl, dinv, invd, b1, hb, N);
    gemm2_mfma_k<<<(N + 127) / 128, 256, 0, stream>>>((const short*)hb, W2T, dinv, t2q, scl2, wsc2, N);
    agg2_k<<<(N + 3) / 4, 256, 0, stream>>>(t2q, nseg, csr, wsc2, scl2, dinv, invd, b2, out, N);
}

// Round 9
// 318.777 us; speedup vs baseline: 1.4768x; 1.1890x over previous
//
#include <hip/hip_runtime.h>
#include <hip/hip_bf16.h>

// GCN 2-layer. R17: R16 regressed (326->379) and pinned the real law:
// gather speed tracks DISTINCT ROWS PER LOAD INSTRUCTION (4 is best; 8 worse;
// 16 worst) — not bytes (R11/R14), not request count (R16), not MLP (R10).
// So: agg1 reverted to proven R11/R14 form (16 lanes x uint2, 4 rows/instr,
// 4 loads/iter ~52us). agg2 rebuilt on the same pattern for 64B int8 rows:
// 16 lanes x uint (4B), quad groups, 4 rows/instr, 4 loads/iter; epilogue =
// one float4 store per quad-0 lane (ql<10 covers 40 cols). Build/gemm1/gemm2
// unchanged from R14/R15-proven versions.

#define FIN 256
#define HDIM 128
#define CDIM 40
#define CAP 8192          // per-bucket edge capacity (mean 4096)
#define EC 8192           // edges per block in scatter

typedef __attribute__((ext_vector_type(8))) short bf16x8;
typedef __attribute__((ext_vector_type(4))) float f32x4;
typedef __attribute__((ext_vector_type(2))) float f32x2;

__device__ inline short f2bf(float f) {               // RNE fp32 -> bf16
    unsigned u = __float_as_uint(f);
    unsigned r = (u + 0x7FFFu + ((u >> 16) & 1u)) >> 16;
    return (short)r;
}
__device__ inline float bflo(unsigned u) { return __uint_as_float(u << 16); }
__device__ inline float bfhi(unsigned u) { return __uint_as_float(u & 0xFFFF0000u); }
__device__ inline f32x2 unpk(unsigned u) { return (f32x2){bflo(u), bfhi(u)}; }
__device__ inline float ub0(unsigned u) { return (float)(u & 255u); }
__device__ inline float ub1(unsigned u) { return (float)((u >> 8) & 255u); }
__device__ inline float ub2(unsigned u) { return (float)((u >> 16) & 255u); }
__device__ inline float ub3(unsigned u) { return (float)(u >> 24); }

// ---- scatter: per-block LDS hist -> global bucket-base alloc -> scatter ----
__global__ __launch_bounds__(1024) void scatter_k(const int* __restrict__ ei, int* __restrict__ gcnt,
                                                  int* __restrict__ bmem, int E, int NBUCK) {
    __shared__ int hist[512];
    __shared__ int base[512];
    const int tid = threadIdx.x;
    for (int t = tid; t < NBUCK; t += 1024) hist[t] = 0;
    __syncthreads();
    const int e0 = blockIdx.x * EC;
    const int e1 = min(E, e0 + EC);
    for (int e = e0 + tid; e < e1; e += 1024) atomicAdd(&hist[ei[E + e] >> 8], 1);
    __syncthreads();
    for (int t = tid; t < NBUCK; t += 1024) base[t] = atomicAdd(&gcnt[t], hist[t]);
    __syncthreads();
    for (int e = e0 + tid; e < e1; e += 1024) {
        int s = ei[e];
        int d = ei[E + e];
        int b = d >> 8;
        int pos = atomicAdd(&base[b], 1);
        bmem[b * CAP + pos] = s | ((d & 255) << 20);   // s < 2^20 (N=100000)
    }
}

// ---- per-bucket CSR build (+ folded weight cast), coalesced writes ----
__global__ __launch_bounds__(256) void p2_build_k(const int* __restrict__ bmem, const int* __restrict__ bcnt,
                                                  int* __restrict__ csr, int2* __restrict__ nseg,
                                                  float* __restrict__ dinv, float* __restrict__ invd,
                                                  const float* __restrict__ W1, const float* __restrict__ W2,
                                                  short* __restrict__ W1T, short* __restrict__ W2T, int N) {
    __shared__ int hist[256], cur[256], sc[256];
    __shared__ int stage[CAP];
    const int b = blockIdx.x;
    const int tid = threadIdx.x;

    // folded castW: grid-stride over both weight matrices
    for (int idx = b * 256 + tid; idx < FIN * HDIM + 48 * HDIM; idx += gridDim.x * 256) {
        if (idx < FIN * HDIM) {
            int k = idx >> 7, n = idx & 127;
            W1T[n * FIN + k] = f2bf(W1[idx]);
        } else {
            int j = idx - FIN * HDIM;
            int c = j >> 7, k = j & 127;
            W2T[j] = (c < CDIM) ? f2bf(W2[k * CDIM + c]) : (short)0;
        }
    }

    int cnt = bcnt[b];
    if (cnt > CAP) cnt = CAP;
    const int* src = bmem + b * CAP;
    hist[tid] = 0;
    __syncthreads();
    for (int j = tid; j < cnt; j += 256) atomicAdd(&hist[src[j] >> 20], 1);
    __syncthreads();
    int v = hist[tid];
    sc[tid] = v;
    __syncthreads();
    for (int off = 1; off < 256; off <<= 1) {
        int t = (tid >= off) ? sc[tid - off] : 0;
        __syncthreads();
        sc[tid] += t;
        __syncthreads();
    }
    int excl = sc[tid] - v;
    cur[tid] = excl;
    int i = b * 256 + tid;
    if (i < N) {
        nseg[i] = make_int2(b * CAP + excl, v);
        float dg = (float)(v + 1);
        dinv[i] = rsqrtf(dg);
        invd[i] = 1.0f / dg;
    }
    __syncthreads();
    for (int j = tid; j < cnt; j += 256) {
        int rec = src[j];
        int pos = atomicAdd(&cur[rec >> 20], 1);
        stage[pos] = rec & 0xFFFFF;
    }
    __syncthreads();
    int* dst = csr + b * CAP;
    for (int j = tid; j < cnt; j += 256) dst[j] = stage[j];
}

// GEMM1 (MFMA bf16): T1 = X(Nx256) @ W1(256x128), quantized to int8 per-row.
// Outputs: T1q (u8 rows, 128B), scl[i]=rowmax/127, wsc[i]=scl[i]*dinv[i].
#define LDSTRIDE 40
__global__ __launch_bounds__(256) void gemm1_mfma_k(const float* __restrict__ X,
                                                    const short* __restrict__ W1T,
                                                    const float* __restrict__ dinv,
                                                    unsigned char* __restrict__ T1q,
                                                    float* __restrict__ scl,
                                                    float* __restrict__ wsc, int N) {
    __shared__ short SH[128 * LDSTRIDE * 2];
    short* As = SH;
    short* Bs = SH + 128 * LDSTRIDE;
    const int tid = threadIdx.x;
    const int lane = tid & 63;
    const int wid = tid >> 6;
    const int w0 = wid & 1, w1 = wid >> 1;
    const int quad = lane >> 4;
    const int l16 = lane & 15;
    const int rowbase = blockIdx.x * 128;
    const int sr = tid >> 1;
    const int sh = tid & 1;

    f32x4 acc[4][4];
#pragma unroll
    for (int a = 0; a < 4; a++)
#pragma unroll
        for (int b = 0; b < 4; b++) acc[a][b] = (f32x4){0.f, 0.f, 0.f, 0.f};

    const int arow = min(rowbase + sr, N - 1);
    const float* xsrc = X + (size_t)arow * FIN + sh * 16;
    const int4* bsrc = (const int4*)(W1T + (size_t)sr * FIN + sh * 16);

    for (int k0 = 0; k0 < FIN; k0 += 32) {
        float vals[16];
        *(float4*)&vals[0]  = *(const float4*)(xsrc + k0);
        *(float4*)&vals[4]  = *(const float4*)(xsrc + k0 + 4);
        *(float4*)&vals[8]  = *(const float4*)(xsrc + k0 + 8);
        *(float4*)&vals[12] = *(const float4*)(xsrc + k0 + 12);
        __hip_bfloat162 tmp2[8];
#pragma unroll
        for (int c = 0; c < 8; c++)
            tmp2[c] = __float22bfloat162_rn(make_float2(vals[2 * c], vals[2 * c + 1]));
        ((int4*)&As[sr * LDSTRIDE + sh * 16])[0] = ((int4*)tmp2)[0];
        ((int4*)&As[sr * LDSTRIDE + sh * 16])[1] = ((int4*)tmp2)[1];
        int4 b0 = bsrc[k0 >> 3];
        int4 b1 = bsrc[(k0 >> 3) + 1];
        ((int4*)&Bs[sr * LDSTRIDE + sh * 16])[0] = b0;
        ((int4*)&Bs[sr * LDSTRIDE + sh * 16])[1] = b1;
        __syncthreads();

        bf16x8 afr[4], bfr[4];
#pragma unroll
        for (int mt = 0; mt < 4; mt++)
            afr[mt] = *(const bf16x8*)&As[(w1 * 64 + mt * 16 + l16) * LDSTRIDE + quad * 8];
#pragma unroll
        for (int nt = 0; nt < 4; nt++)
            bfr[nt] = *(const bf16x8*)&Bs[(w0 * 64 + nt * 16 + l16) * LDSTRIDE + quad * 8];
#pragma unroll
        for (int mt = 0; mt < 4; mt++)
#pragma unroll
            for (int nt = 0; nt < 4; nt++)
                acc[mt][nt] = __builtin_amdgcn_mfma_f32_16x16x32_bf16(afr[mt], bfr[nt], acc[mt][nt], 0, 0, 0);
        __syncthreads();
    }

    // ---- int8 per-row quantization epilogue ----
    unsigned char* qbuf = (unsigned char*)SH;                 // 16KB staging
    float* rmaxb = (float*)((char*)SH + 16384);               // [2][128] half-row maxes
#pragma unroll
    for (int mt = 0; mt < 4; mt++) {
#pragma unroll
        for (int r = 0; r < 4; r++) {
            float m = fabsf(acc[mt][0][r]);
            m = fmaxf(m, fabsf(acc[mt][1][r]));
            m = fmaxf(m, fabsf(acc[mt][2][r]));
            m = fmaxf(m, fabsf(acc[mt][3][r]));
#pragma unroll
            for (int off = 1; off < 16; off <<= 1) m = fmaxf(m, __shfl_xor(m, off));
            rmaxb[w0 * 128 + w1 * 64 + mt * 16 + quad * 4 + r] = m;
        }
    }
    __syncthreads();
    if (tid < 128) {
        int grow = rowbase + tid;
        if (grow < N) {
            float rv = fmaxf(rmaxb[tid], rmaxb[128 + tid]);
            float s = rv * (1.f / 127.f);
            scl[grow] = s;
            wsc[grow] = s * dinv[grow];
        }
    }
#pragma unroll
    for (int mt = 0; mt < 4; mt++) {
#pragma unroll
        for (int r = 0; r < 4; r++) {
            const int row = w1 * 64 + mt * 16 + quad * 4 + r;
            float rv = fmaxf(rmaxb[row], rmaxb[128 + row]);
            float qinv = rv > 0.f ? 127.f / rv : 0.f;
#pragma unroll
            for (int nt = 0; nt < 4; nt++) {
                int qi = (int)rintf(acc[mt][nt][r] * qinv) + 128;
                qi = qi < 0 ? 0 : (qi > 255 ? 255 : qi);
                qbuf[row * 128 + w0 * 64 + nt * 16 + l16] = (unsigned char)qi;
            }
        }
    }
    __syncthreads();
#pragma unroll
    for (int it = 0; it < 4; it++) {
        int idx = tid + it * 256;            // 1024 x 16B = 16KB
        int row = idx >> 3;
        if (rowbase + row < N)
            ((uint4*)(T1q + (size_t)(rowbase + row) * 128))[idx & 7] = ((const uint4*)qbuf)[idx];
    }
}

// agg1: wave/node, int8 gather (uint2 = 8 cols/lane; 4 rows per load instr).
// acc_c = sum_j wsc[s_j]*u_jc ; true sum recovered via -128*asum bias.
__global__ __launch_bounds__(256) void agg1_k(const unsigned char* __restrict__ T1q, const int2* __restrict__ nseg,
                                              const int* __restrict__ csr, const float* __restrict__ wsc,
                                              const float* __restrict__ scl, const float* __restrict__ dinv,
                                              const float* __restrict__ invd, const float* __restrict__ b1,
                                              unsigned* __restrict__ Hb, int N) {
    const int lane = threadIdx.x & 63;
    const int quad = lane >> 4;
    const int ql = lane & 15;
    const int i = blockIdx.x * 4 + (threadIdx.x >> 6);
    if (i >= N) return;
    const int2 sg = nseg[i];
    const int e0 = sg.x, deg = sg.y;
    int sv = 0; float wv = 0.f;
    if (lane < deg) { sv = csr[e0 + lane]; wv = wsc[sv]; }   // lanes>=deg: wv=0

    const uint2* rowp = (const uint2*)T1q;   // 16 uint2 per 128B row
    uint2 us = rowp[i * 16 + ql];            // self row
    const float sscale = scl[i];

    f32x2 acc[4]; float asum = 0.f;
#pragma unroll
    for (int t = 0; t < 4; t++) acc[t] = (f32x2){0.f, 0.f};

    const int dmain = deg < 64 ? deg : 64;
    for (int j = 0; j < dmain; j += 16) {
        const int i0 = j + quad, i1 = j + 4 + quad, i2 = j + 8 + quad, i3 = j + 12 + quad;
        int s0 = __shfl(sv, i0); int s1 = __shfl(sv, i1);
        int s2 = __shfl(sv, i2); int s3 = __shfl(sv, i3);
        float w0 = __shfl(wv, i0); float w1 = __shfl(wv, i1);
        float w2 = __shfl(wv, i2); float w3 = __shfl(wv, i3);
        w0 = (i0 < dmain) ? w0 : 0.f;
        w1 = (i1 < dmain) ? w1 : 0.f;
        w2 = (i2 < dmain) ? w2 : 0.f;
        w3 = (i3 < dmain) ? w3 : 0.f;
        uint2 u0 = rowp[s0 * 16 + ql];
        uint2 u1 = rowp[s1 * 16 + ql];
        uint2 u2 = rowp[s2 * 16 + ql];
        uint2 u3 = rowp[s3 * 16 + ql];
        asum += w0 + w1 + w2 + w3;
        f32x2 W0 = (f32x2){w0, w0}, W1v = (f32x2){w1, w1}, W2v = (f32x2){w2, w2}, W3v = (f32x2){w3, w3};
        acc[0] += W0 * (f32x2){ub0(u0.x), ub1(u0.x)} + W1v * (f32x2){ub0(u1.x), ub1(u1.x)}
                + W2v * (f32x2){ub0(u2.x), ub1(u2.x)} + W3v * (f32x2){ub0(u3.x), ub1(u3.x)};
        acc[1] += W0 * (f32x2){ub2(u0.x), ub3(u0.x)} + W1v * (f32x2){ub2(u1.x), ub3(u1.x)}
                + W2v * (f32x2){ub2(u2.x), ub3(u2.x)} + W3v * (f32x2){ub2(u3.x), ub3(u3.x)};
        acc[2] += W0 * (f32x2){ub0(u0.y), ub1(u0.y)} + W1v * (f32x2){ub0(u1.y), ub1(u1.y)}
                + W2v * (f32x2){ub0(u2.y), ub1(u2.y)} + W3v * (f32x2){ub0(u3.y), ub1(u3.y)};
        acc[3] += W0 * (f32x2){ub2(u0.y), ub3(u0.y)} + W1v * (f32x2){ub2(u1.y), ub3(u1.y)}
                + W2v * (f32x2){ub2(u2.y), ub3(u2.y)} + W3v * (f32x2){ub2(u3.y), ub3(u3.y)};
    }
    const int eEnd = e0 + deg;
    for (int e = e0 + 64; e < eEnd; e += 4) {          // rare tail deg > 64
        int idx = e + quad;
        int cl = idx < eEnd ? idx : eEnd - 1;
        int sj = csr[cl];
        float wj = (idx < eEnd) ? wsc[sj] : 0.f;
        uint2 u = rowp[sj * 16 + ql];
        asum += wj;
        f32x2 Wj = (f32x2){wj, wj};
        acc[0] += Wj * (f32x2){ub0(u.x), ub1(u.x)};
        acc[1] += Wj * (f32x2){ub2(u.x), ub3(u.x)};
        acc[2] += Wj * (f32x2){ub0(u.y), ub1(u.y)};
        acc[3] += Wj * (f32x2){ub2(u.y), ub3(u.y)};
    }
#pragma unroll
    for (int t = 0; t < 4; t++) {
        acc[t].x += __shfl_xor(acc[t].x, 16); acc[t].y += __shfl_xor(acc[t].y, 16);
        acc[t].x += __shfl_xor(acc[t].x, 32); acc[t].y += __shfl_xor(acc[t].y, 32);
    }
    asum += __shfl_xor(asum, 16);
    asum += __shfl_xor(asum, 32);

    const float di = dinv[i];
    const float sf2 = invd[i] * sscale;
    const float K = -128.f * (sf2 + di * asum);
    float4 bA = *(const float4*)(b1 + ql * 8);
    float4 bB = *(const float4*)(b1 + ql * 8 + 4);
    float o0 = fmaxf(bA.x + sf2 * ub0(us.x) + di * acc[0].x + K, 0.f);
    float o1 = fmaxf(bA.y + sf2 * ub1(us.x) + di * acc[0].y + K, 0.f);
    float o2 = fmaxf(bA.z + sf2 * ub2(us.x) + di * acc[1].x + K, 0.f);
    float o3 = fmaxf(bA.w + sf2 * ub3(us.x) + di * acc[1].y + K, 0.f);
    float o4 = fmaxf(bB.x + sf2 * ub0(us.y) + di * acc[2].x + K, 0.f);
    float o5 = fmaxf(bB.y + sf2 * ub1(us.y) + di * acc[2].y + K, 0.f);
    float o6 = fmaxf(bB.z + sf2 * ub2(us.y) + di * acc[3].x + K, 0.f);
    float o7 = fmaxf(bB.w + sf2 * ub3(us.y) + di * acc[3].y + K, 0.f);
    uint4 pk;
    pk.x = ((unsigned)(unsigned short)f2bf(o0)) | (((unsigned)(unsigned short)f2bf(o1)) << 16);
    pk.y = ((unsigned)(unsigned short)f2bf(o2)) | (((unsigned)(unsigned short)f2bf(o3)) << 16);
    pk.z = ((unsigned)(unsigned short)f2bf(o4)) | (((unsigned)(unsigned short)f2bf(o5)) << 16);
    pk.w = ((unsigned)(unsigned short)f2bf(o6)) | (((unsigned)(unsigned short)f2bf(o7)) << 16);
    if (quad == 0) ((uint4*)(Hb + (size_t)i * 64))[ql] = pk;
}

// GEMM2 (MFMA bf16): T2 = H(Nx128 bf16) @ W2T(48x128)^T, int8-quantized
// per-row into 64B-aligned rows (cols 40..63 pad = 128, self-cancelling).
__global__ __launch_bounds__(256) void gemm2_mfma_k(const short* __restrict__ Hb,
                                                    const short* __restrict__ W2T,
                                                    const float* __restrict__ dinv,
                                                    unsigned char* __restrict__ T2q,
                                                    float* __restrict__ scl2,
                                                    float* __restrict__ wsc2, int N) {
    __shared__ short As[128 * LDSTRIDE];
    __shared__ short Bs[48 * LDSTRIDE];
    const int tid = threadIdx.x;
    const int lane = tid & 63;
    const int wid = tid >> 6;
    const int quad = lane >> 4;
    const int l16 = lane & 15;
    const int rowbase = blockIdx.x * 128;
    const int sr = tid >> 1;
    const int sh = tid & 1;

    f32x4 acc[2][3];
#pragma unroll
    for (int a = 0; a < 2; a++)
#pragma unroll
        for (int b = 0; b < 3; b++) acc[a][b] = (f32x4){0.f, 0.f, 0.f, 0.f};

    const int arow = min(rowbase + sr, N - 1);
    const int4* asrc = (const int4*)(Hb + (size_t)arow * HDIM + sh * 16);
    const int br = tid >> 1, bh = tid & 1;   // for tid < 96
    const int4* bsrc = (const int4*)(W2T + br * HDIM + bh * 16);

    for (int k0 = 0; k0 < HDIM; k0 += 32) {
        int4 a0 = asrc[k0 >> 3];
        int4 a1 = asrc[(k0 >> 3) + 1];
        ((int4*)&As[sr * LDSTRIDE + sh * 16])[0] = a0;
        ((int4*)&As[sr * LDSTRIDE + sh * 16])[1] = a1;
        if (tid < 96) {
            int4 b0 = bsrc[k0 >> 3];
            int4 b1 = bsrc[(k0 >> 3) + 1];
            ((int4*)&Bs[br * LDSTRIDE + bh * 16])[0] = b0;
            ((int4*)&Bs[br * LDSTRIDE + bh * 16])[1] = b1;
        }
        __syncthreads();
        bf16x8 afr[2], bfr[3];
#pragma unroll
        for (int mt = 0; mt < 2; mt++)
            afr[mt] = *(const bf16x8*)&As[(wid * 32 + mt * 16 + l16) * LDSTRIDE + quad * 8];
#pragma unroll
        for (int nt = 0; nt < 3; nt++)
            bfr[nt] = *(const bf16x8*)&Bs[(nt * 16 + l16) * LDSTRIDE + quad * 8];
#pragma unroll
        for (int mt = 0; mt < 2; mt++)
#pragma unroll
            for (int nt = 0; nt < 3; nt++)
                acc[mt][nt] = __builtin_amdgcn_mfma_f32_16x16x32_bf16(afr[mt], bfr[nt], acc[mt][nt], 0, 0, 0);
        __syncthreads();
    }

    // ---- int8 per-row quantization epilogue ----
    unsigned char* qbuf = (unsigned char*)As;                 // 8KB staging
#pragma unroll
    for (int mt = 0; mt < 2; mt++) {
#pragma unroll
        for (int r = 0; r < 4; r++) {
            float m = fmaxf(fmaxf(fabsf(acc[mt][0][r]), fabsf(acc[mt][1][r])), fabsf(acc[mt][2][r]));
#pragma unroll
            for (int off = 1; off < 16; off <<= 1) m = fmaxf(m, __shfl_xor(m, off));
            const int row = wid * 32 + mt * 16 + quad * 4 + r;
            const int grow = rowbase + row;
            const float qinv = m > 0.f ? 127.f / m : 0.f;
            if (l16 == 0 && grow < N) {
                float s = m * (1.f / 127.f);
                scl2[grow] = s;
                wsc2[grow] = s * dinv[grow];
            }
            int q0 = (int)rintf(acc[mt][0][r] * qinv) + 128;
            int q1 = (int)rintf(acc[mt][1][r] * qinv) + 128;
            int q2 = (int)rintf(acc[mt][2][r] * qinv) + 128;
            q0 = q0 < 0 ? 0 : (q0 > 255 ? 255 : q0);
            q1 = q1 < 0 ? 0 : (q1 > 255 ? 255 : q1);
            q2 = q2 < 0 ? 0 : (q2 > 255 ? 255 : q2);
            qbuf[row * 64 + l16]      = (unsigned char)q0;
            qbuf[row * 64 + 16 + l16] = (unsigned char)q1;
            qbuf[row * 64 + 32 + l16] = (unsigned char)q2;
        }
    }
    for (int idx = tid; idx < 2048; idx += 256)               // pad cols 48..63
        qbuf[(idx >> 4) * 64 + 48 + (idx & 15)] = (unsigned char)128;
    __syncthreads();
#pragma unroll
    for (int it = 0; it < 2; it++) {
        int idx = tid + it * 256;            // 512 x 16B = 8KB
        int row = idx >> 2;
        if (rowbase + row < N)
            ((uint4*)(T2q + (size_t)(rowbase + row) * 64))[idx & 3] = ((const uint4*)qbuf)[idx];
    }
}

// agg2: wave/node, int8 64B rows, 16 lanes x uint (4B) = 4 rows per load
// instruction (the proven-optimal divergence). Grain-16, 4 loads/iter.
// Epilogue: quad-0 lane ql holds cols 4ql..4ql+3 -> one float4 store (ql<10).
__global__ __launch_bounds__(256) void agg2_k(const unsigned char* __restrict__ T2q, const int2* __restrict__ nseg,
                                              const int* __restrict__ csr, const float* __restrict__ wsc2,
                                              const float* __restrict__ scl2, const float* __restrict__ dinv,
                                              const float* __restrict__ invd, const float* __restrict__ b2,
                                              float* __restrict__ OUT, int N) {
    const int lane = threadIdx.x & 63;
    const int quad = lane >> 4;
    const int ql = lane & 15;
    const int i = blockIdx.x * 4 + (threadIdx.x >> 6);
    if (i >= N) return;
    const int2 sg = nseg[i];
    const int e0 = sg.x, deg = sg.y;
    int sv = 0; float wv = 0.f;
    if (lane < deg) { sv = csr[e0 + lane]; wv = wsc2[sv]; }

    const unsigned* rowp = (const unsigned*)T2q;   // 16 uints per 64B row
    unsigned us = rowp[i * 16 + ql];               // self: cols 4ql..4ql+3
    const float sscale = scl2[i];

    f32x2 acc[2]; float asum = 0.f;
    acc[0] = (f32x2){0.f, 0.f};
    acc[1] = (f32x2){0.f, 0.f};

    const int dmain = deg < 64 ? deg : 64;
    for (int j = 0; j < dmain; j += 16) {
        const int i0 = j + quad, i1 = j + 4 + quad, i2 = j + 8 + quad, i3 = j + 12 + quad;
        int s0 = __shfl(sv, i0); int s1 = __shfl(sv, i1);
        int s2 = __shfl(sv, i2); int s3 = __shfl(sv, i3);
        float w0 = __shfl(wv, i0); float w1 = __shfl(wv, i1);
        float w2 = __shfl(wv, i2); float w3 = __shfl(wv, i3);
        w0 = (i0 < dmain) ? w0 : 0.f;
        w1 = (i1 < dmain) ? w1 : 0.f;
        w2 = (i2 < dmain) ? w2 : 0.f;
        w3 = (i3 < dmain) ? w3 : 0.f;
        unsigned u0 = rowp[s0 * 16 + ql];
        unsigned u1 = rowp[s1 * 16 + ql];
        unsigned u2 = rowp[s2 * 16 + ql];
        unsigned u3 = rowp[s3 * 16 + ql];
        asum += w0 + w1 + w2 + w3;
        f32x2 W0 = (f32x2){w0, w0}, W1v = (f32x2){w1, w1}, W2v = (f32x2){w2, w2}, W3v = (f32x2){w3, w3};
        acc[0] += W0 * (f32x2){ub0(u0), ub1(u0)} + W1v * (f32x2){ub0(u1), ub1(u1)}
                + W2v * (f32x2){ub0(u2), ub1(u2)} + W3v * (f32x2){ub0(u3), ub1(u3)};
        acc[1] += W0 * (f32x2){ub2(u0), ub3(u0)} + W1v * (f32x2){ub2(u1), ub3(u1)}
                + W2v * (f32x2){ub2(u2), ub3(u2)} + W3v * (f32x2){ub2(u3), ub3(u3)};
    }
    const int eEnd = e0 + deg;
    for (int e = e0 + 64; e < eEnd; e += 4) {          // rare tail deg > 64
        int idx = e + quad;
        int cl = idx < eEnd ? idx : eEnd - 1;
        int sj = csr[cl];
        float wj = (idx < eEnd) ? wsc2[sj] : 0.f;
        unsigned u = rowp[sj * 16 + ql];
        asum += wj;
        f32x2 Wj = (f32x2){wj, wj};
        acc[0] += Wj * (f32x2){ub0(u), ub1(u)};
        acc[1] += Wj * (f32x2){ub2(u), ub3(u)};
    }
#pragma unroll
    for (int t = 0; t < 2; t++) {
        acc[t].x += __shfl_xor(acc[t].x, 16); acc[t].y += __shfl_xor(acc[t].y, 16);
        acc[t].x += __shfl_xor(acc[t].x, 32); acc[t].y += __shfl_xor(acc[t].y, 32);
    }
    asum += __shfl_xor(asum, 16);
    asum += __shfl_xor(asum, 32);

    if (quad == 0 && ql < 10) {              // cols 4ql..4ql+3 (40 total)
        const float di = dinv[i];
        const float sf2 = invd[i] * sscale;
        const float K = -128.f * (sf2 + di * asum);
        float4 bb = *(const float4*)(b2 + ql * 4);
        float4 o;
        o.x = bb.x + sf2 * ub0(us) + di * acc[0].x + K;
        o.y = bb.y + sf2 * ub1(us) + di * acc[0].y + K;
        o.z = bb.z + sf2 * ub2(us) + di * acc[1].x + K;
        o.w = bb.w + sf2 * ub3(us) + di * acc[1].y + K;
        *(float4*)(OUT + (size_t)i * CDIM + ql * 4) = o;
    }
}

extern "C" void kernel_launch(void* const* d_in, const int* in_sizes, int n_in,
                              void* d_out, int out_size, void* d_ws, size_t ws_size,
                              hipStream_t stream) {
    const float* x   = (const float*)d_in[0];
    const int*   ei  = (const int*)d_in[1];     // int32 in harness
    const float* W1  = (const float*)d_in[2];
    const float* b1  = (const float*)d_in[3];
    const float* W2  = (const float*)d_in[4];
    const float* b2  = (const float*)d_in[5];
    float*       out = (float*)d_out;

    const int Hd  = in_sizes[3];            // 128
    const int Fin = in_sizes[2] / Hd;       // 256
    const int N   = in_sizes[0] / Fin;      // 100000
    const int E   = in_sizes[1] / 2;        // 1600000

    const int NBUCK = (N + 255) / 256;      // 391
    const int NB1   = (E + EC - 1) / EC;    // 196

    char* base = (char*)d_ws;
    size_t off = 0;
    auto alloc = [&](size_t bytes) -> void* {
        void* p = base + off;
        off += (bytes + 255) & ~(size_t)255;
        return p;
    };
    // region A: bmem (prep only), overlaid later by t1q (gemm1 onward)
    size_t bmemB = (size_t)NBUCK * CAP * 4;
    size_t t1qB  = (size_t)N * 128;
    size_t regA  = bmemB > t1qB ? bmemB : t1qB;
    char* pA = (char*)alloc(regA);
    int*           bmem = (int*)pA;
    unsigned char* t1q  = (unsigned char*)pA;

    int*      gcnt = (int*)alloc((size_t)NBUCK * 4);
    int*      csr  = (int*)alloc((size_t)NBUCK * CAP * 4);
    int2*     nseg = (int2*)alloc((size_t)N * 8);
    float*    dinv = (float*)alloc((size_t)N * 4);
    float*    invd = (float*)alloc((size_t)N * 4);
    float*    scl  = (float*)alloc((size_t)N * 4);
    float*    wsc  = (float*)alloc((size_t)N * 4);
    float*    scl2 = (float*)alloc((size_t)N * 4);
    float*    wsc2 = (float*)alloc((size_t)N * 4);
    short*    W1T  = (short*)alloc((size_t)HDIM * FIN * 2);
    short*    W2T  = (short*)alloc((size_t)48 * HDIM * 2);
    unsigned* hb   = (unsigned*)alloc((size_t)N * HDIM * 2);
    unsigned char* t2q = (unsigned char*)alloc((size_t)N * 64);

    hipMemsetAsync(gcnt, 0, (size_t)NBUCK * 4, stream);
    scatter_k<<<NB1, 1024, 0, stream>>>(ei, gcnt, bmem, E, NBUCK);
    p2_build_k<<<NBUCK, 256, 0, stream>>>(bmem, gcnt, csr, nseg, dinv, invd, W1, W2, W1T, W2T, N);

    gemm1_mfma_k<<<(N + 127) / 128, 256, 0, stream>>>(x, W1T, dinv, t1q, scl, wsc, N);
    agg1_k<<<(N + 3) / 4, 256, 0, stream>>>(t1q, nseg, csr, wsc, scl, dinv, invd, b1, hb, N);
    gemm2_mfma_k<<<(N + 127) / 128, 256, 0, stream>>>((const short*)hb, W2T, dinv, t2q, scl2, wsc2, N);
    agg2_k<<<(N + 3) / 4, 256, 0, stream>>>(t2q, nseg, csr, wsc2, scl2, dinv, invd, b2, out, N);
}